// Round 4
// baseline (2641.654 us; speedup 1.0000x reference)
//
#include <hip/hip_runtime.h>
#include <math.h>

// Problem constants (B=8, N=4096, C=256, K=32)
constexpr int B_ = 8;
constexpr int N_ = 4096;
constexpr int C_ = 256;
constexpr int K_ = 32;
constexpr int D_ = 2 * C_;          // 512
constexpr int ROWS = B_ * N_;       // 32768

// ws layout:
//   fp   : float[ROWS * D_]   (64 MB)  feat_pos: feat=[:,0:256], pos=[:,256:512]
//   tkv2 : float[ROWS * 64]   (8 MB)   per-row, per-col-half top-32 values
//   tki2 : int  [ROWS * 64]   (8 MB)   per-row, per-col-half top-32 indices

// ---------------------------------------------------------------------------
// Kernel 1: feat_pos = x @ W^T + bias   (fp32 tiled GEMM)
// ---------------------------------------------------------------------------
__global__ __launch_bounds__(256, 4) void k_gemm_bias(
    const float* __restrict__ x, const float* __restrict__ W,
    const float* __restrict__ bias, float* __restrict__ fp)
{
    __shared__ float At[64 * 64];   // [kk][row]
    __shared__ float Bt[64 * 64];   // [kk][dcol]

    const int tid = threadIdx.x;
    const int w = tid >> 6, l = tid & 63;
    const int tr = tid >> 4, tc = tid & 15;
    const int d0 = blockIdx.x * 64;
    const int r0 = blockIdx.y * 64;

    float4 acc0 = {0,0,0,0}, acc1 = {0,0,0,0}, acc2 = {0,0,0,0}, acc3 = {0,0,0,0};

    for (int kc = 0; kc < 4; ++kc) {
        __syncthreads();
        #pragma unroll
        for (int i = 0; i < 4; ++i) {
            const int kloc = w * 16 + 4 * i;
            float4 a = *(const float4*)&x[(size_t)(r0 + l) * C_ + kc * 64 + kloc];
            At[(kloc + 0) * 64 + l] = a.x;
            At[(kloc + 1) * 64 + l] = a.y;
            At[(kloc + 2) * 64 + l] = a.z;
            At[(kloc + 3) * 64 + l] = a.w;
            float4 b = *(const float4*)&W[(size_t)(d0 + l) * C_ + kc * 64 + kloc];
            Bt[(kloc + 0) * 64 + l] = b.x;
            Bt[(kloc + 1) * 64 + l] = b.y;
            Bt[(kloc + 2) * 64 + l] = b.z;
            Bt[(kloc + 3) * 64 + l] = b.w;
        }
        __syncthreads();
        #pragma unroll 8
        for (int kk = 0; kk < 64; ++kk) {
            float4 a = *(const float4*)&At[kk * 64 + 4 * tr];
            float4 b = *(const float4*)&Bt[kk * 64 + 4 * tc];
            acc0.x = fmaf(a.x, b.x, acc0.x); acc0.y = fmaf(a.x, b.y, acc0.y);
            acc0.z = fmaf(a.x, b.z, acc0.z); acc0.w = fmaf(a.x, b.w, acc0.w);
            acc1.x = fmaf(a.y, b.x, acc1.x); acc1.y = fmaf(a.y, b.y, acc1.y);
            acc1.z = fmaf(a.y, b.z, acc1.z); acc1.w = fmaf(a.y, b.w, acc1.w);
            acc2.x = fmaf(a.z, b.x, acc2.x); acc2.y = fmaf(a.z, b.y, acc2.y);
            acc2.z = fmaf(a.z, b.z, acc2.z); acc2.w = fmaf(a.z, b.w, acc2.w);
            acc3.x = fmaf(a.w, b.x, acc3.x); acc3.y = fmaf(a.w, b.y, acc3.y);
            acc3.z = fmaf(a.w, b.z, acc3.z); acc3.w = fmaf(a.w, b.w, acc3.w);
        }
    }

    float4 bv = *(const float4*)&bias[d0 + 4 * tc];
    float4 o;
    o.x = acc0.x + bv.x; o.y = acc0.y + bv.y; o.z = acc0.z + bv.z; o.w = acc0.w + bv.w;
    *(float4*)&fp[(size_t)(r0 + 4 * tr + 0) * D_ + d0 + 4 * tc] = o;
    o.x = acc1.x + bv.x; o.y = acc1.y + bv.y; o.z = acc1.z + bv.z; o.w = acc1.w + bv.w;
    *(float4*)&fp[(size_t)(r0 + 4 * tr + 1) * D_ + d0 + 4 * tc] = o;
    o.x = acc2.x + bv.x; o.y = acc2.y + bv.y; o.z = acc2.z + bv.z; o.w = acc2.w + bv.w;
    *(float4*)&fp[(size_t)(r0 + 4 * tr + 2) * D_ + d0 + 4 * tc] = o;
    o.x = acc3.x + bv.x; o.y = acc3.y + bv.y; o.z = acc3.z + bv.z; o.w = acc3.w + bv.w;
    *(float4*)&fp[(size_t)(r0 + 4 * tr + 3) * D_ + d0 + 4 * tc] = o;
}

// ---------------------------------------------------------------------------
// Kernel 2: normalize pos rows in place. One wave per row.
// ---------------------------------------------------------------------------
__global__ __launch_bounds__(256) void k_norm(float* __restrict__ fp)
{
    const int w = threadIdx.x >> 6, l = threadIdx.x & 63;
    const int row = blockIdx.x * 4 + w;
    float* p = &fp[(size_t)row * D_ + C_];
    float4 v = *(float4*)&p[4 * l];
    float s = v.x * v.x + v.y * v.y + v.z * v.z + v.w * v.w;
    #pragma unroll
    for (int m = 1; m < 64; m <<= 1) s += __shfl_xor(s, m);
    float scale = 1.0f / fmaxf(sqrtf(s), 1e-12f);
    v.x *= scale; v.y *= scale; v.z *= scale; v.w *= scale;
    *(float4*)&p[4 * l] = v;
}

// ---------------------------------------------------------------------------
// Kernel 3: fused sim (pos @ pos^T per batch, fp32) + register-direct top-32.
// Grid 512 = (256 row-tiles) x (2 column halves): 2 blocks/CU, 16 waves/CU.
// Block: 128 rows x 2048 cols, 512 thr, 4x8 acc. LDS = 64 KB (At+Bt only).
// A wave's 64 lanes hold its 16 rows x 128 cols in acc regs -> scan via
// ballot/shuffle, no LDS round trip. Per-half top-32 written to tkv2/tki2;
// k_out merges the two halves (disjoint index ranges -> exact union top-32).
// Per-thread cols {4tc..+3} u {64+4tc..+3}: 16B lane stride -> 2-way banks.
// ---------------------------------------------------------------------------
__global__ __launch_bounds__(512, 4) void k_simtopk(
    const float* __restrict__ fp, float* __restrict__ tkv2, int* __restrict__ tki2)
{
    __shared__ float At[64 * 128];      // [kk][row]  32 KB
    __shared__ float Bt[64 * 128];      // [kk][col]  32 KB

    const int tid  = threadIdx.x;
    const int lane = tid & 63;
    const int wave = tid >> 6;          // 0..7
    const int half = lane >> 5;         // 0/1
    const int hl   = lane & 31;
    const int tr   = tid >> 4;          // 0..31 -> 4-row group
    const int tc   = tid & 15;
    const int bx   = blockIdx.x;
    const int r0   = (bx >> 1) * 128;
    const int chalf = bx & 1;
    const int cbase = chalf * 2048;
    const int batch = r0 >> 12;
    const size_t bbase = (size_t)batch * N_;

    const int srow = tid & 127;         // staging row/col owner
    const int kq   = tid >> 7;          // 0..3 k-quarter

    // Top-32 state: slot p (lanes of half h) holds row r_loc = 2p + h of this
    // wave's 16 rows. 32 entries distributed across the 32 lanes of the half.
    float sval[8]; int sidx[8]; float mv[8];
    #pragma unroll
    for (int p = 0; p < 8; ++p) { sval[p] = -1e30f; sidx[p] = 0x7FFFFFFF; mv[p] = -1e30f; }

    for (int ct = 0; ct < 16; ++ct) {
        const int c0 = cbase + ct * 128;
        float acc[4][8];
        #pragma unroll
        for (int i = 0; i < 4; ++i)
            #pragma unroll
            for (int j = 0; j < 8; ++j) acc[i][j] = 0.0f;

        for (int kc = 0; kc < 4; ++kc) {
            __syncthreads();
            #pragma unroll
            for (int j = 0; j < 4; ++j) {
                const int kl = kq * 16 + j * 4;
                float4 a = *(const float4*)&fp[(size_t)(r0 + srow) * D_ + C_ + kc * 64 + kl];
                At[(kl + 0) * 128 + srow] = a.x;
                At[(kl + 1) * 128 + srow] = a.y;
                At[(kl + 2) * 128 + srow] = a.z;
                At[(kl + 3) * 128 + srow] = a.w;
                float4 b = *(const float4*)&fp[(bbase + c0 + srow) * D_ + C_ + kc * 64 + kl];
                Bt[(kl + 0) * 128 + srow] = b.x;
                Bt[(kl + 1) * 128 + srow] = b.y;
                Bt[(kl + 2) * 128 + srow] = b.z;
                Bt[(kl + 3) * 128 + srow] = b.w;
            }
            __syncthreads();
            #pragma unroll 4
            for (int kk = 0; kk < 64; ++kk) {
                float4 av = *(const float4*)&At[kk * 128 + 4 * tr];
                float4 b0 = *(const float4*)&Bt[kk * 128 + 4 * tc];
                float4 b1 = *(const float4*)&Bt[kk * 128 + 64 + 4 * tc];
                const float ar[4] = {av.x, av.y, av.z, av.w};
                const float br[8] = {b0.x, b0.y, b0.z, b0.w, b1.x, b1.y, b1.z, b1.w};
                #pragma unroll
                for (int i = 0; i < 4; ++i)
                    #pragma unroll
                    for (int j = 0; j < 8; ++j)
                        acc[i][j] = fmaf(ar[i], br[j], acc[i][j]);
            }
        }

        // ---- register-direct scan (no barriers needed: regs + cross-lane only)
        #pragma unroll
        for (int rl_ = 0; rl_ < 16; ++rl_) {
            const int g = rl_ >> 2, i = rl_ & 3, p = rl_ >> 1, h = rl_ & 1;
            const bool ing = ((lane >> 4) == g);
            float thr = __shfl(mv[p], h << 5);
            // col groups: j 0..3 = cols 4tc+j (0..63), j 4..7 = 64+4tc+(j-4).
            // Group A fully precedes group B; within a group, __ffsll order =
            // ascending tc = ascending col -> stable-top-k tie order kept.
            #pragma unroll
            for (int j = 0; j < 8; ++j) {
                float vj = acc[i][j];
                for (;;) {
                    unsigned long long cm = __ballot(ing && vj > thr);
                    if (!cm) break;
                    const int src = __ffsll((unsigned long long)cm) - 1;
                    const float cv = __shfl(vj, src);
                    const int cc = c0 + ((j < 4) ? j : (60 + j)) + 4 * (src & 15);
                    // eviction target: half-h lane(s) holding the current min
                    unsigned long long em = __ballot((half == h) && (sval[p] == thr));
                    int evl = __ffsll((unsigned long long)em) - 1;
                    if (__popcll(em) > 1) {
                        // exact-tie on min value: evict the largest index (stable)
                        int ti = ((half == h) && (sval[p] == thr)) ? sidx[p] : -1;
                        int tl = lane;
                        #pragma unroll
                        for (int s = 1; s < 32; s <<= 1) {
                            int oi = __shfl_xor(ti, s);
                            int ol = __shfl_xor(tl, s);
                            if (oi > ti) { ti = oi; tl = ol; }
                        }
                        evl = __shfl(tl, h << 5);   // broadcast for consistency
                    }
                    if (lane == evl) { sval[p] = cv; sidx[p] = cc; }
                    if (lane == src) vj = -1e30f;   // consume candidate
                    float rv = sval[p];
                    #pragma unroll
                    for (int s = 1; s < 32; s <<= 1)
                        rv = fminf(rv, __shfl_xor(rv, s));
                    mv[p] = rv;
                    thr = __shfl(rv, h << 5);
                }
            }
        }
    }

    // Writeout per-half top-32 (set semantics; order-free downstream)
    #pragma unroll
    for (int p = 0; p < 8; ++p) {
        const int row = r0 + wave * 16 + 2 * p + half;
        tkv2[((size_t)row << 6) + (chalf << 5) + hl] = sval[p];
        tki2[((size_t)row << 6) + (chalf << 5) + hl] = sidx[p];
    }
}

// ---------------------------------------------------------------------------
// Kernel 4: merge 2x top-32 -> top-32, softmax, gather feat, weighted sum.
// One block per row. Wave 0 merges 64 candidates by repeated argmax
// (ties -> lower index = stable top-k; halves have disjoint indices).
// ---------------------------------------------------------------------------
__global__ __launch_bounds__(256) void k_out(
    const float* __restrict__ fp, const float* __restrict__ tkv2,
    const int* __restrict__ tki2, float* __restrict__ out)
{
    __shared__ float attn[32];
    __shared__ float vtmp[32];
    __shared__ int   sid[32];
    const int row = blockIdx.x;
    const int batch = row >> 12;
    const int tid = threadIdx.x;

    if (tid < 64) {
        float v = tkv2[((size_t)row << 6) + tid];
        int   ix = tki2[((size_t)row << 6) + tid];
        for (int s = 0; s < 32; ++s) {
            float rv = v; int ri = ix;
            #pragma unroll
            for (int t = 1; t < 64; t <<= 1) {
                float ov = __shfl_xor(rv, t);
                int   oi = __shfl_xor(ri, t);
                if (ov > rv || (ov == rv && oi < ri)) { rv = ov; ri = oi; }
            }
            if (tid == 0) { vtmp[s] = rv; sid[s] = ri; }
            if (ix == ri) v = -1e30f;   // indices unique across halves
        }
    }
    __syncthreads();

    if (tid < 32) {
        const float m = vtmp[0];        // sorted descending: [0] is the max
        float e = expf(vtmp[tid] - m);
        float sum = e;
        #pragma unroll
        for (int s = 16; s >= 1; s >>= 1) sum += __shfl_xor(sum, s);
        attn[tid] = e / sum;
    }
    __syncthreads();

    const float* featb = fp + (size_t)batch * N_ * D_;
    float acc = 0.0f;
    #pragma unroll 8
    for (int k = 0; k < 32; ++k)
        acc = fmaf(attn[k], featb[(size_t)sid[k] * D_ + tid], acc);
    out[(size_t)row * C_ + tid] = acc;
}

// ---------------------------------------------------------------------------
extern "C" void kernel_launch(void* const* d_in, const int* in_sizes, int n_in,
                              void* d_out, int out_size, void* d_ws, size_t ws_size,
                              hipStream_t stream)
{
    const float* x    = (const float*)d_in[0];
    const float* W    = (const float*)d_in[1];
    const float* bias = (const float*)d_in[2];
    // d_in[3] = k (=32), compile-time constant here.

    float* fp   = (float*)d_ws;                      // ROWS * D_
    float* tkv2 = fp + (size_t)ROWS * D_;            // ROWS * 64
    int*   tki2 = (int*)(tkv2 + (size_t)ROWS * 64);  // ROWS * 64
    float* out  = (float*)d_out;

    k_gemm_bias<<<dim3(D_ / 64, ROWS / 64), 256, 0, stream>>>(x, W, bias, fp);
    k_norm<<<ROWS / 4, 256, 0, stream>>>(fp);
    k_simtopk<<<ROWS / 64, 512, 0, stream>>>(fp, tkv2, tki2);   // 512 blocks
    k_out<<<ROWS, 256, 0, stream>>>(fp, tkv2, tki2, out);
}

// Round 6
// 1707.454 us; speedup vs baseline: 1.5471x; 1.5471x over previous
//
#include <hip/hip_runtime.h>
#include <math.h>

// Problem constants (B=8, N=4096, C=256, K=32)
constexpr int B_ = 8;
constexpr int N_ = 4096;
constexpr int C_ = 256;
constexpr int D_ = 2 * C_;          // 512
constexpr int ROWS = B_ * N_;       // 32768

// ws layout:
//   fp   : float[ROWS * D_]   (64 MB)  feat_pos: feat=[:,0:256], pos=[:,256:512]
//   tkv2 : float[ROWS * 64]   (8 MB)   per-row, per-col-half top-32 values (sorted desc)
//   tki2 : int  [ROWS * 64]   (8 MB)
// d_out doubles as posT scratch: posT[batch][k][col] (33.5 MB), dead before k_out.

// ---------------------------------------------------------------------------
// Kernel 1: feat_pos = x @ W^T + bias   (fp32 tiled GEMM)
// ---------------------------------------------------------------------------
__global__ __launch_bounds__(256, 4) void k_gemm_bias(
    const float* __restrict__ x, const float* __restrict__ W,
    const float* __restrict__ bias, float* __restrict__ fp)
{
    __shared__ float At[64 * 64];   // [kk][row]
    __shared__ float Bt[64 * 64];   // [kk][dcol]

    const int tid = threadIdx.x;
    const int w = tid >> 6, l = tid & 63;
    const int tr = tid >> 4, tc = tid & 15;
    const int d0 = blockIdx.x * 64;
    const int r0 = blockIdx.y * 64;

    float4 acc0 = {0,0,0,0}, acc1 = {0,0,0,0}, acc2 = {0,0,0,0}, acc3 = {0,0,0,0};

    for (int kc = 0; kc < 4; ++kc) {
        __syncthreads();
        #pragma unroll
        for (int i = 0; i < 4; ++i) {
            const int kloc = w * 16 + 4 * i;
            float4 a = *(const float4*)&x[(size_t)(r0 + l) * C_ + kc * 64 + kloc];
            At[(kloc + 0) * 64 + l] = a.x;
            At[(kloc + 1) * 64 + l] = a.y;
            At[(kloc + 2) * 64 + l] = a.z;
            At[(kloc + 3) * 64 + l] = a.w;
            float4 b = *(const float4*)&W[(size_t)(d0 + l) * C_ + kc * 64 + kloc];
            Bt[(kloc + 0) * 64 + l] = b.x;
            Bt[(kloc + 1) * 64 + l] = b.y;
            Bt[(kloc + 2) * 64 + l] = b.z;
            Bt[(kloc + 3) * 64 + l] = b.w;
        }
        __syncthreads();
        #pragma unroll 8
        for (int kk = 0; kk < 64; ++kk) {
            float4 a = *(const float4*)&At[kk * 64 + 4 * tr];
            float4 b = *(const float4*)&Bt[kk * 64 + 4 * tc];
            acc0.x = fmaf(a.x, b.x, acc0.x); acc0.y = fmaf(a.x, b.y, acc0.y);
            acc0.z = fmaf(a.x, b.z, acc0.z); acc0.w = fmaf(a.x, b.w, acc0.w);
            acc1.x = fmaf(a.y, b.x, acc1.x); acc1.y = fmaf(a.y, b.y, acc1.y);
            acc1.z = fmaf(a.y, b.z, acc1.z); acc1.w = fmaf(a.y, b.w, acc1.w);
            acc2.x = fmaf(a.z, b.x, acc2.x); acc2.y = fmaf(a.z, b.y, acc2.y);
            acc2.z = fmaf(a.z, b.z, acc2.z); acc2.w = fmaf(a.z, b.w, acc2.w);
            acc3.x = fmaf(a.w, b.x, acc3.x); acc3.y = fmaf(a.w, b.y, acc3.y);
            acc3.z = fmaf(a.w, b.z, acc3.z); acc3.w = fmaf(a.w, b.w, acc3.w);
        }
    }

    float4 bv = *(const float4*)&bias[d0 + 4 * tc];
    float4 o;
    o.x = acc0.x + bv.x; o.y = acc0.y + bv.y; o.z = acc0.z + bv.z; o.w = acc0.w + bv.w;
    *(float4*)&fp[(size_t)(r0 + 4 * tr + 0) * D_ + d0 + 4 * tc] = o;
    o.x = acc1.x + bv.x; o.y = acc1.y + bv.y; o.z = acc1.z + bv.z; o.w = acc1.w + bv.w;
    *(float4*)&fp[(size_t)(r0 + 4 * tr + 1) * D_ + d0 + 4 * tc] = o;
    o.x = acc2.x + bv.x; o.y = acc2.y + bv.y; o.z = acc2.z + bv.z; o.w = acc2.w + bv.w;
    *(float4*)&fp[(size_t)(r0 + 4 * tr + 2) * D_ + d0 + 4 * tc] = o;
    o.x = acc3.x + bv.x; o.y = acc3.y + bv.y; o.z = acc3.z + bv.z; o.w = acc3.w + bv.w;
    *(float4*)&fp[(size_t)(r0 + 4 * tr + 3) * D_ + d0 + 4 * tc] = o;
}

// ---------------------------------------------------------------------------
// Kernel 2: normalize pos rows in place. One wave per row.
// BIT-EXACT copy of the round-1..4 version: 4 elems/lane partial + 64-lane
// butterfly. DO NOT change the reduction order — top-k boundary picks depend
// on pos bits (round-5 failure: a different norm order flipped one pick).
// ---------------------------------------------------------------------------
__global__ __launch_bounds__(256) void k_norm(float* __restrict__ fp)
{
    const int w = threadIdx.x >> 6, l = threadIdx.x & 63;
    const int row = blockIdx.x * 4 + w;
    float* p = &fp[(size_t)row * D_ + C_];
    float4 v = *(float4*)&p[4 * l];
    float s = v.x * v.x + v.y * v.y + v.z * v.z + v.w * v.w;
    #pragma unroll
    for (int m = 1; m < 64; m <<= 1) s += __shfl_xor(s, m);
    float scale = 1.0f / fmaxf(sqrtf(s), 1e-12f);
    v.x *= scale; v.y *= scale; v.z *= scale; v.w *= scale;
    *(float4*)&p[4 * l] = v;
}

// ---------------------------------------------------------------------------
// Kernel 2b: pure transpose pos -> posT[batch][k][col]. Values untouched.
// 16 rows/block; LDS tile; coalesced float4 on both global sides.
// ---------------------------------------------------------------------------
__global__ __launch_bounds__(256) void k_transp(
    const float* __restrict__ fp, float* __restrict__ posT)
{
    __shared__ float P[16 * 260];       // padded stride 260
    const int tid = threadIdx.x;
    const int r0 = blockIdx.x * 16;
    const int row = tid >> 4;           // 0..15
    const int cb  = (tid & 15) * 16;    // 16 floats per thread
    const int batch = r0 >> 12;
    const int rloc = r0 & (N_ - 1);

    const float* src = &fp[(size_t)(r0 + row) * D_ + C_ + cb];
    float4 q0 = *(const float4*)&src[0];
    float4 q1 = *(const float4*)&src[4];
    float4 q2 = *(const float4*)&src[8];
    float4 q3 = *(const float4*)&src[12];
    float* pr = &P[row * 260 + cb];
    *(float4*)&pr[0]  = q0; *(float4*)&pr[4]  = q1;
    *(float4*)&pr[8]  = q2; *(float4*)&pr[12] = q3;
    __syncthreads();

    const int k = tid;                  // 0..255
    float o[16];
    #pragma unroll
    for (int r = 0; r < 16; ++r) o[r] = P[r * 260 + k];
    float* dst = &posT[((size_t)batch * C_ + k) * (size_t)N_ + rloc];
    float4 w0 = {o[0],o[1],o[2],o[3]};
    float4 w1 = {o[4],o[5],o[6],o[7]};
    float4 w2 = {o[8],o[9],o[10],o[11]};
    float4 w3 = {o[12],o[13],o[14],o[15]};
    *(float4*)&dst[0]  = w0; *(float4*)&dst[4]  = w1;
    *(float4*)&dst[8]  = w2; *(float4*)&dst[12] = w3;
}

// ---------------------------------------------------------------------------
// Kernel 3: fused sim (posT k-major, fp32) + sorted-register top-32.
// Grid 512 = 256 row-tiles x 2 column halves; 512 thr; 4x8 acc; LDS 64 KB.
// Same FMA accumulation order (kc, kk ascending) as the passing round-4
// kernel -> sim values bit-identical -> identical top-k picks.
// Top-32 per row kept SORTED desc across the 32 lanes of a wave-half;
// insertion = shfl up-shift + 2 cndmask. Fast per-row skip via per-lane
// 8-val max + one ballot.
// ---------------------------------------------------------------------------
__global__ __launch_bounds__(512, 4) void k_simtopk(
    const float* __restrict__ posT, float* __restrict__ tkv2, int* __restrict__ tki2)
{
    __shared__ float At[64 * 128];      // [kk][row] 32 KB
    __shared__ float Bt[64 * 128];      // [kk][col] 32 KB

    const int tid  = threadIdx.x;
    const int lane = tid & 63;
    const int wave = tid >> 6;          // 0..7
    const int half = lane >> 5;         // 0/1
    const int hl   = lane & 31;
    const int tr   = tid >> 4;          // 0..31
    const int tc   = tid & 15;
    const int bx   = blockIdx.x;
    const int r0   = (bx >> 1) * 128;
    const int chalf = bx & 1;
    const int cbase = chalf * 2048;
    const int batch = r0 >> 12;
    const int rloc  = r0 & (N_ - 1);
    const float* PT = posT + (size_t)batch * C_ * N_;

    const int skk = tid >> 5;           // 0..15  k sub-row
    const int sco = (tid & 31) * 4;     // col offset

    // Sorted top-32: lane hl of half h holds rank-hl (v,idx) of row 2p+h.
    float sv[8]; int si[8];
    #pragma unroll
    for (int p = 0; p < 8; ++p) { sv[p] = -1e30f; si[p] = 0; }

    for (int ct = 0; ct < 16; ++ct) {
        const int c0 = cbase + ct * 128;
        float acc[4][8];
        #pragma unroll
        for (int i = 0; i < 4; ++i)
            #pragma unroll
            for (int j = 0; j < 8; ++j) acc[i][j] = 0.0f;

        for (int kc = 0; kc < 4; ++kc) {
            __syncthreads();
            #pragma unroll
            for (int j = 0; j < 4; ++j) {
                const int kk = j * 16 + skk;
                const size_t gro = (size_t)(kc * 64 + kk) * N_;
                float4 a = *(const float4*)&PT[gro + rloc + sco];
                *(float4*)&At[kk * 128 + sco] = a;
                float4 b = *(const float4*)&PT[gro + c0 + sco];
                *(float4*)&Bt[kk * 128 + sco] = b;
            }
            __syncthreads();
            #pragma unroll 4
            for (int kk = 0; kk < 64; ++kk) {
                float4 av = *(const float4*)&At[kk * 128 + 4 * tr];
                float4 b0 = *(const float4*)&Bt[kk * 128 + 4 * tc];
                float4 b1 = *(const float4*)&Bt[kk * 128 + 64 + 4 * tc];
                const float ar[4] = {av.x, av.y, av.z, av.w};
                const float br[8] = {b0.x, b0.y, b0.z, b0.w, b1.x, b1.y, b1.z, b1.w};
                #pragma unroll
                for (int i = 0; i < 4; ++i)
                    #pragma unroll
                    for (int j = 0; j < 8; ++j)
                        acc[i][j] = fmaf(ar[i], br[j], acc[i][j]);
            }
        }

        // per-lane row maxima for the fast skip
        float mx[4];
        #pragma unroll
        for (int i = 0; i < 4; ++i) {
            float m0 = fmaxf(fmaxf(acc[i][0], acc[i][1]), fmaxf(acc[i][2], acc[i][3]));
            float m1 = fmaxf(fmaxf(acc[i][4], acc[i][5]), fmaxf(acc[i][6], acc[i][7]));
            mx[i] = fmaxf(m0, m1);
        }

        // scan: local row rl_ = 4g+i lives in lane group g; stored slot p, half h
        #pragma unroll
        for (int rl_ = 0; rl_ < 16; ++rl_) {
            const int g = rl_ >> 2, i = rl_ & 3;
            const int p = rl_ >> 1, h = rl_ & 1;
            const bool ing = ((lane >> 4) == g);
            const int tlane = (h << 5) + 31;
            float thr = __shfl(sv[p], tlane);
            if (__ballot(ing && mx[i] > thr) == 0ULL) continue;
            #pragma unroll
            for (int j = 0; j < 8; ++j) {
                float vj = acc[i][j];
                for (;;) {
                    unsigned long long cm = __ballot(ing && vj > thr);
                    if (cm == 0ULL) break;
                    const int src = __ffsll(cm) - 1;
                    const float cv = __shfl(vj, src);
                    const int   cc = c0 + ((j < 4) ? j : (60 + j)) + 4 * (src & 15);
                    const float upv = __shfl(sv[p], (lane - 1) & 63);
                    const int   upi = __shfl(si[p], (lane - 1) & 63);
                    if (half == h) {
                        const float upe = (hl == 0) ? 3.0e38f : upv;
                        if (upe < cv)        { sv[p] = upv; si[p] = upi; }   // shift down
                        else if (sv[p] < cv) { sv[p] = cv;  si[p] = cc;  }   // take
                    }
                    thr = __shfl(sv[p], tlane);
                    if (lane == src) vj = -1e30f;   // consume
                }
            }
        }
    }

    // Writeout: sorted desc, lane hl = rank hl of its half's list
    #pragma unroll
    for (int p = 0; p < 8; ++p) {
        const int row = r0 + wave * 16 + 2 * p + half;
        tkv2[((size_t)row << 6) + (chalf << 5) + hl] = sv[p];
        tki2[((size_t)row << 6) + (chalf << 5) + hl] = si[p];
    }
}

// ---------------------------------------------------------------------------
// Kernel 4: bitonic-merge two sorted-32 halves -> top-32, softmax, gather.
// Load half0 reversed (ascending) + half1 (descending) = bitonic 64-seq;
// 6 compare-exchange stages sort descending; lanes 0..31 = top-32.
// ---------------------------------------------------------------------------
__global__ __launch_bounds__(256) void k_out(
    const float* __restrict__ fp, const float* __restrict__ tkv2,
    const int* __restrict__ tki2, float* __restrict__ out)
{
    __shared__ float attn[32];
    __shared__ int   sid[32];
    const int row = blockIdx.x;
    const int batch = row >> 12;
    const int tid = threadIdx.x;

    if (tid < 64) {
        const int srcix = (tid < 32) ? (31 - tid) : tid;
        float v  = tkv2[((size_t)row << 6) + srcix];
        int   ix = tki2[((size_t)row << 6) + srcix];
        #pragma unroll
        for (int d = 32; d >= 1; d >>= 1) {
            float ov = __shfl_xor(v, d);
            int   oi = __shfl_xor(ix, d);
            const bool keepmax = ((tid & d) == 0);
            const bool otherwins = (ov > v) || (ov == v && oi < ix);
            if (keepmax == otherwins) { v = ov; ix = oi; }
        }
        const float m = __shfl(v, 0);   // global max at lane 0
        if (tid < 32) {
            float e = expf(v - m);
            float sum = e;
            #pragma unroll
            for (int s2 = 16; s2 >= 1; s2 >>= 1) sum += __shfl_xor(sum, s2);
            attn[tid] = e / sum;
            sid[tid]  = ix;
        }
    }
    __syncthreads();

    const float* featb = fp + (size_t)batch * N_ * D_;
    float acc = 0.0f;
    #pragma unroll 8
    for (int k = 0; k < 32; ++k)
        acc = fmaf(attn[k], featb[(size_t)sid[k] * D_ + tid], acc);
    out[(size_t)row * C_ + tid] = acc;
}

// ---------------------------------------------------------------------------
extern "C" void kernel_launch(void* const* d_in, const int* in_sizes, int n_in,
                              void* d_out, int out_size, void* d_ws, size_t ws_size,
                              hipStream_t stream)
{
    const float* x    = (const float*)d_in[0];
    const float* W    = (const float*)d_in[1];
    const float* bias = (const float*)d_in[2];
    // d_in[3] = k (=32), compile-time constant here.

    float* fp   = (float*)d_ws;                      // ROWS * D_
    float* tkv2 = fp + (size_t)ROWS * D_;            // ROWS * 64
    int*   tki2 = (int*)(tkv2 + (size_t)ROWS * 64);  // ROWS * 64
    float* out  = (float*)d_out;
    float* posT = (float*)d_out;                     // scratch until k_out

    k_gemm_bias<<<dim3(D_ / 64, ROWS / 64), 256, 0, stream>>>(x, W, bias, fp);
    k_norm<<<ROWS / 4, 256, 0, stream>>>(fp);
    k_transp<<<ROWS / 16, 256, 0, stream>>>(fp, posT);
    k_simtopk<<<ROWS / 64, 512, 0, stream>>>(posT, tkv2, tki2);
    k_out<<<ROWS, 256, 0, stream>>>(fp, tkv2, tki2, out);
}